// Round 3
// baseline (666.401 us; speedup 1.0000x reference)
//
#include <hip/hip_runtime.h>
#include <stdint.h>

// LocalWindowAttention: B=2,T=4096,D=2048,H=16,HK=4,HD=128,WIN=512
// R3: fused attention with XOR-swizzled LDS (swizzle applied via per-lane
// global source addresses, since global_load_lds pins lane->LDS slot).
// K/V chunks: phys_chunk = chunk ^ (row&15). P overlay: chunk ^ ((row>>1)|((row&1)<<3)).

typedef unsigned short u16;
typedef __attribute__((ext_vector_type(8))) short frag8;   // 8 bf16 = 4 VGPRs
typedef __attribute__((ext_vector_type(4))) float f32x4;   // MFMA acc

#define TILE 128

__device__ __forceinline__ u16 f2bf(float f) {
  union { float f; unsigned u; } c; c.f = f;
  unsigned u = c.u;
  return (u16)((u + 0x7fffu + ((u >> 16) & 1u)) >> 16);
}

// async global->LDS, 16B per lane; LDS dest = wave-uniform base + lane*16
__device__ __forceinline__ void async16(const u16* g, u16* l) {
  __builtin_amdgcn_global_load_lds((const __attribute__((address_space(1))) void*)g,
                                   (__attribute__((address_space(3))) void*)l, 16, 0, 0);
}

// ---- m97-style 128x128 GEMM core: A [M,K] row-major bf16, Bt = B^T [N,K] row-major
__device__ __forceinline__ void gemm_core(const u16* __restrict__ A, int lda,
                                          const u16* __restrict__ Bt, int ldb,
                                          int K, u16* As, u16* Bs, f32x4 acc[4][4]) {
  const int tid = threadIdx.x;
  const int lane = tid & 63, wave = tid >> 6;
  const int wr = wave >> 1, wc = wave & 1;
  const int quad = lane >> 4, l16 = lane & 15;
#pragma unroll
  for (int i = 0; i < 4; ++i)
#pragma unroll
    for (int j = 0; j < 4; ++j) acc[i][j] = (f32x4){0.f, 0.f, 0.f, 0.f};

  const int row0 = tid >> 2, offc = (tid & 3) * 8;  // 128 rows x 32 k, 16B chunks
  for (int k0 = 0; k0 < K; k0 += 32) {
#pragma unroll
    for (int r = 0; r < 2; ++r) {
      int row = r * 64 + row0;
      async16(A + (long)row * lda + k0 + offc, As + r * 2048 + wave * 512);
      async16(Bt + (long)row * ldb + k0 + offc, Bs + r * 2048 + wave * 512);
    }
    __syncthreads();
    frag8 af[4], bf[4];
#pragma unroll
    for (int i = 0; i < 4; ++i)
      af[i] = *(const frag8*)(As + (wr * 64 + i * 16 + l16) * 32 + quad * 8);
#pragma unroll
    for (int j = 0; j < 4; ++j)
      bf[j] = *(const frag8*)(Bs + (wc * 64 + j * 16 + l16) * 32 + quad * 8);
#pragma unroll
    for (int i = 0; i < 4; ++i)
#pragma unroll
      for (int j = 0; j < 4; ++j)
        acc[i][j] = __builtin_amdgcn_mfma_f32_16x16x32_bf16(af[i], bf[j], acc[i][j], 0, 0, 0);
    __syncthreads();
  }
}

#define EPI_COORDS                                             \
  const int lane = threadIdx.x & 63, wave = threadIdx.x >> 6;  \
  const int wr = wave >> 1, wc = wave & 1;                     \
  const int quad = lane >> 4, l16 = lane & 15;

__global__ __launch_bounds__(256) void k_gemm_bf16(const u16* __restrict__ A, int lda,
                                                   const u16* __restrict__ Bt, int ldb,
                                                   u16* __restrict__ C, int ldc, int K) {
  __shared__ alignas(16) u16 smem[2 * TILE * 32];
  f32x4 acc[4][4];
  gemm_core(A + (long)blockIdx.x * TILE * lda, lda,
            Bt + (long)blockIdx.y * TILE * ldb, ldb, K, smem, smem + TILE * 32, acc);
  EPI_COORDS
  u16* Ct = C + (long)blockIdx.x * TILE * ldc + (long)blockIdx.y * TILE;
#pragma unroll
  for (int i = 0; i < 4; ++i)
#pragma unroll
    for (int j = 0; j < 4; ++j) {
      int r0 = wr * 64 + i * 16 + quad * 4, cc = wc * 64 + j * 16 + l16;
#pragma unroll
      for (int r = 0; r < 4; ++r) Ct[(long)(r0 + r) * ldc + cc] = f2bf(acc[i][j][r]);
    }
}

// writes C^T: contiguous 4-element store per acc tile (for V^T layout)
__global__ __launch_bounds__(256) void k_gemm_bf16t(const u16* __restrict__ A, int lda,
                                                    const u16* __restrict__ Bt, int ldb,
                                                    u16* __restrict__ Ct, int ldct, int K) {
  __shared__ alignas(16) u16 smem[2 * TILE * 32];
  f32x4 acc[4][4];
  gemm_core(A + (long)blockIdx.x * TILE * lda, lda,
            Bt + (long)blockIdx.y * TILE * ldb, ldb, K, smem, smem + TILE * 32, acc);
  EPI_COORDS
  u16* Cb = Ct + (long)blockIdx.y * TILE * ldct + (long)blockIdx.x * TILE;
#pragma unroll
  for (int i = 0; i < 4; ++i)
#pragma unroll
    for (int j = 0; j < 4; ++j) {
      int n = wc * 64 + j * 16 + l16, m0 = wr * 64 + i * 16 + quad * 4;
      ushort4 o;
      o.x = f2bf(acc[i][j][0]); o.y = f2bf(acc[i][j][1]);
      o.z = f2bf(acc[i][j][2]); o.w = f2bf(acc[i][j][3]);
      *(ushort4*)(Cb + (long)n * ldct + m0) = o;
    }
}

__global__ __launch_bounds__(256) void k_gemm_f32(const u16* __restrict__ A, int lda,
                                                  const u16* __restrict__ Bt, int ldb,
                                                  float* __restrict__ C, int ldc, int K) {
  __shared__ alignas(16) u16 smem[2 * TILE * 32];
  f32x4 acc[4][4];
  gemm_core(A + (long)blockIdx.x * TILE * lda, lda,
            Bt + (long)blockIdx.y * TILE * ldb, ldb, K, smem, smem + TILE * 32, acc);
  EPI_COORDS
  float* Ct = C + (long)blockIdx.x * TILE * ldc + (long)blockIdx.y * TILE;
#pragma unroll
  for (int i = 0; i < 4; ++i)
#pragma unroll
    for (int j = 0; j < 4; ++j) {
      int r0 = wr * 64 + i * 16 + quad * 4, cc = wc * 64 + j * 16 + l16;
#pragma unroll
      for (int r = 0; r < 4; ++r) Ct[(long)(r0 + r) * ldc + cc] = acc[i][j][r];
    }
}

// ---- fused local-window attention --------------------------------------
// grid: x = qi (q 128-row block), y = blk, z = b*16 + h. Wave owns 32 q-rows.
// LDS swizzle: Ks/Vs phys 16B-chunk = logical chunk ^ (row&15)  (banks ~2-way)
//              P  phys chunk = logical chunk ^ ((row&15)>>1 | (row&1)<<3)
__global__ __launch_bounds__(256, 2) void k_attn(const u16* __restrict__ qb,
                                                 const u16* __restrict__ kb,
                                                 const u16* __restrict__ vT,
                                                 u16* __restrict__ O) {
  __shared__ alignas(16) u16 Ks[128 * 128];  // [key][hd] swizzled; P overlays
  __shared__ alignas(16) u16 Vs[128 * 128];  // [hd][key] swizzled
  const int tid = threadIdx.x, lane = tid & 63, wave = tid >> 6;
  const int quad = lane >> 4, l16 = lane & 15;
  const int qi = blockIdx.x, blk = blockIdx.y;
  const int b = blockIdx.z >> 4, h = blockIdx.z & 15, hk = h >> 2;
  const long tok_q = (long)b * 4096 + blk * 512 + qi * 128;
  const float scale = 0.08838834764831845f;  // 1/sqrt(128)

  // Q fragments for this wave's 32 rows, all of HD=128 (held across chunks)
  frag8 qf[2][4];
#pragma unroll
  for (int i = 0; i < 2; ++i)
#pragma unroll
    for (int kt = 0; kt < 4; ++kt)
      qf[i][kt] = *(const frag8*)(qb + (tok_q + wave * 32 + i * 16 + l16) * 2048 +
                                  h * 128 + kt * 32 + quad * 8);

  f32x4 o_acc[2][8];
  float m_r[2][4], l_r[2][4];
#pragma unroll
  for (int i = 0; i < 2; ++i) {
#pragma unroll
    for (int j = 0; j < 8; ++j) o_acc[i][j] = (f32x4){0.f, 0.f, 0.f, 0.f};
#pragma unroll
    for (int r = 0; r < 4; ++r) { m_r[i][r] = -1e30f; l_r[i][r] = 0.f; }
  }

  const int row_s = tid >> 4;                      // staging row (0..15 per r2 step)
  const int off_sw = (((tid & 15) ^ row_s) * 8);   // swizzled source chunk offset
  u16* PsW = Ks + wave * 4096;                     // wave's 32x128 P region
  const int psw = (l16 >> 1) | ((l16 & 1) << 3);   // P swizzle for read rows

  for (int ci = (blk ? qi : 4); ci <= 4 + qi; ++ci) {
    const long tok_k = (long)b * 4096 + (blk - 1) * 512 + ci * 128;
    const int mode = (ci == qi) ? 1 : ((ci == 4 + qi) ? 2 : 0);

    // stage K chunk [128 key][128 hd] and V chunk [128 hd][128 key], swizzled
#pragma unroll
    for (int r2 = 0; r2 < 8; ++r2) {
      int row = r2 * 16 + row_s;
      async16(kb + (tok_k + row) * 512 + hk * 128 + off_sw, Ks + r2 * 2048 + wave * 512);
      async16(vT + ((long)hk * 128 + row) * 8192 + tok_k + off_sw, Vs + r2 * 2048 + wave * 512);
    }
    __syncthreads();

    // S = Q @ K^T  (32 rows x 128 keys per wave)
    f32x4 s_acc[2][8];
#pragma unroll
    for (int i = 0; i < 2; ++i)
#pragma unroll
      for (int j = 0; j < 8; ++j) s_acc[i][j] = (f32x4){0.f, 0.f, 0.f, 0.f};
#pragma unroll
    for (int kt = 0; kt < 4; ++kt) {
      frag8 bfr[8];
#pragma unroll
      for (int j = 0; j < 8; ++j)
        bfr[j] = *(const frag8*)(Ks + (j * 16 + l16) * 128 + ((kt * 4 + quad) ^ l16) * 8);
#pragma unroll
      for (int i = 0; i < 2; ++i)
#pragma unroll
        for (int j = 0; j < 8; ++j)
          s_acc[i][j] = __builtin_amdgcn_mfma_f32_16x16x32_bf16(qf[i][kt], bfr[j], s_acc[i][j], 0, 0, 0);
    }

    // scale + mask + per-row chunk max
    float mc[2][4];
#pragma unroll
    for (int i = 0; i < 2; ++i)
#pragma unroll
      for (int r = 0; r < 4; ++r) mc[i][r] = -1e30f;
#pragma unroll
    for (int i = 0; i < 2; ++i)
#pragma unroll
      for (int j = 0; j < 8; ++j)
#pragma unroll
        for (int r = 0; r < 4; ++r) {
          int rl = wave * 32 + i * 16 + quad * 4 + r;  // row within 128-q-block
          int lk = j * 16 + l16;                       // key within chunk
          bool ok = (mode == 0) || (mode == 1 ? (lk > rl) : (lk <= rl));
          float s = ok ? s_acc[i][j][r] * scale : -1e30f;
          s_acc[i][j][r] = s;
          mc[i][r] = fmaxf(mc[i][r], s);
        }
#pragma unroll
    for (int o = 1; o < 16; o <<= 1)
#pragma unroll
      for (int i = 0; i < 2; ++i)
#pragma unroll
        for (int r = 0; r < 4; ++r)
          mc[i][r] = fmaxf(mc[i][r], __shfl_xor(mc[i][r], o));

    // online-softmax update
    float alpha[2][4];
#pragma unroll
    for (int i = 0; i < 2; ++i)
#pragma unroll
      for (int r = 0; r < 4; ++r) {
        float mn = fmaxf(m_r[i][r], mc[i][r]);
        alpha[i][r] = __expf(m_r[i][r] - mn);
        m_r[i][r] = mn;
        l_r[i][r] *= alpha[i][r];
      }
#pragma unroll
    for (int i = 0; i < 2; ++i)
#pragma unroll
      for (int j = 0; j < 8; ++j)
#pragma unroll
        for (int r = 0; r < 4; ++r) o_acc[i][j][r] *= alpha[i][r];

    float ps[2][4];
#pragma unroll
    for (int i = 0; i < 2; ++i)
#pragma unroll
      for (int r = 0; r < 4; ++r) ps[i][r] = 0.f;
#pragma unroll
    for (int i = 0; i < 2; ++i)
#pragma unroll
      for (int j = 0; j < 8; ++j)
#pragma unroll
        for (int r = 0; r < 4; ++r) {
          float s = s_acc[i][j][r];
          float e = __expf(s - m_r[i][r]);
          e = (s == -1e30f) ? 0.f : e;
          s_acc[i][j][r] = e;
          ps[i][r] += e;
        }
#pragma unroll
    for (int o = 1; o < 16; o <<= 1)
#pragma unroll
      for (int i = 0; i < 2; ++i)
#pragma unroll
        for (int r = 0; r < 4; ++r) ps[i][r] += __shfl_xor(ps[i][r], o);
#pragma unroll
    for (int i = 0; i < 2; ++i)
#pragma unroll
      for (int r = 0; r < 4; ++r) l_r[i][r] += ps[i][r];

    __syncthreads();  // all waves done reading Ks before P overlays it

    // P: C-layout regs -> LDS [row][key], swizzled (wave-private region)
#pragma unroll
    for (int i = 0; i < 2; ++i)
#pragma unroll
      for (int j = 0; j < 8; ++j)
#pragma unroll
        for (int r = 0; r < 4; ++r) {
          int rl = i * 16 + quad * 4 + r;
          int sw = ((rl & 15) >> 1) | ((rl & 1) << 3);
          int cc = 2 * j + (l16 >> 3);
          PsW[rl * 128 + ((cc ^ sw) * 8) + (l16 & 7)] = f2bf(s_acc[i][j][r]);
        }

    // O += P @ V
#pragma unroll
    for (int kt = 0; kt < 4; ++kt) {
      frag8 pf[2], vf[8];
#pragma unroll
      for (int i = 0; i < 2; ++i)
        pf[i] = *(const frag8*)(PsW + (i * 16 + l16) * 128 + (((kt * 4 + quad) ^ psw) * 8));
#pragma unroll
      for (int j = 0; j < 8; ++j)
        vf[j] = *(const frag8*)(Vs + (j * 16 + l16) * 128 + ((kt * 4 + quad) ^ l16) * 8);
#pragma unroll
      for (int i = 0; i < 2; ++i)
#pragma unroll
        for (int j = 0; j < 8; ++j)
          o_acc[i][j] = __builtin_amdgcn_mfma_f32_16x16x32_bf16(pf[i], vf[j], o_acc[i][j], 0, 0, 0);
    }
    __syncthreads();  // before next chunk's staging overwrites Ks/Vs
  }

  // epilogue: O / l
  float inv[2][4];
#pragma unroll
  for (int i = 0; i < 2; ++i)
#pragma unroll
    for (int r = 0; r < 4; ++r) inv[i][r] = 1.0f / l_r[i][r];
#pragma unroll
  for (int i = 0; i < 2; ++i)
#pragma unroll
    for (int j = 0; j < 8; ++j)
#pragma unroll
      for (int r = 0; r < 4; ++r) {
        long row = tok_q + wave * 32 + i * 16 + quad * 4 + r;
        O[row * 2048 + h * 128 + j * 16 + l16] = f2bf(o_acc[i][j][r] * inv[i][r]);
      }
}

__global__ void k_convert(const float4* __restrict__ x, ushort4* __restrict__ xb) {
  int i = blockIdx.x * 256 + threadIdx.x;
  float4 f = x[i];
  ushort4 o;
  o.x = f2bf(f.x); o.y = f2bf(f.y); o.z = f2bf(f.z); o.w = f2bf(f.w);
  xb[i] = o;
}

// W [K,N] fp32 -> W^T [N,K] bf16
__global__ void k_transpose(const float* __restrict__ W, u16* __restrict__ WT, int K, int N) {
  __shared__ float sh[32][33];
  int n0 = blockIdx.x * 32, k0 = blockIdx.y * 32;
  int tx = threadIdx.x, ty = threadIdx.y;  // (32, 8)
#pragma unroll
  for (int i = 0; i < 32; i += 8) sh[ty + i][tx] = W[(long)(k0 + ty + i) * N + n0 + tx];
  __syncthreads();
#pragma unroll
  for (int i = 0; i < 32; i += 8) WT[(long)(n0 + ty + i) * K + k0 + tx] = f2bf(sh[tx][ty + i]);
}

extern "C" void kernel_launch(void* const* d_in, const int* in_sizes, int n_in,
                              void* d_out, int out_size, void* d_ws, size_t ws_size,
                              hipStream_t stream) {
  const float* x  = (const float*)d_in[0];
  const float* Wq = (const float*)d_in[1];
  const float* Wk = (const float*)d_in[2];
  const float* Wv = (const float*)d_in[3];
  const float* Wo = (const float*)d_in[4];
  float* out = (float*)d_out;

  const long BT = 8192, D = 2048, NKV = 512;
  size_t off = 0;
  auto alloc = [&](size_t bytes) -> char* {
    off = (off + 255) & ~(size_t)255;
    char* p = (char*)d_ws + off;
    off += bytes;
    return p;
  };

  u16* xb  = (u16*)alloc((size_t)BT * D * 2);  // reused as attention output
  u16* WqT = (u16*)alloc((size_t)D * D * 2);
  u16* WkT = (u16*)alloc((size_t)NKV * D * 2);
  u16* WvT = (u16*)alloc((size_t)NKV * D * 2);
  u16* WoT = (u16*)alloc((size_t)D * D * 2);
  u16* qb  = (u16*)alloc((size_t)BT * D * 2);
  u16* kb  = (u16*)alloc((size_t)BT * NKV * 2);
  u16* vT  = (u16*)alloc((size_t)NKV * BT * 2);
  u16* Oa  = xb;

  k_convert<<<16384, 256, 0, stream>>>((const float4*)x, (ushort4*)xb);
  dim3 tb(32, 8);
  k_transpose<<<dim3(64, 64), tb, 0, stream>>>(Wq, WqT, 2048, 2048);
  k_transpose<<<dim3(16, 64), tb, 0, stream>>>(Wk, WkT, 2048, 512);
  k_transpose<<<dim3(16, 64), tb, 0, stream>>>(Wv, WvT, 2048, 512);
  k_transpose<<<dim3(64, 64), tb, 0, stream>>>(Wo, WoT, 2048, 2048);

  k_gemm_bf16 <<<dim3(64, 16), 256, 0, stream>>>(xb, 2048, WqT, 2048, qb, 2048, 2048);
  k_gemm_bf16 <<<dim3(64, 4),  256, 0, stream>>>(xb, 2048, WkT, 2048, kb, 512, 2048);
  k_gemm_bf16t<<<dim3(64, 4),  256, 0, stream>>>(xb, 2048, WvT, 2048, vT, 8192, 2048);

  k_attn<<<dim3(4, 8, 32), 256, 0, stream>>>(qb, kb, vT, Oa);

  k_gemm_f32<<<dim3(64, 16), 256, 0, stream>>>(Oa, 2048, WoT, 2048, out, 2048, 2048);
}

// Round 4
// 664.984 us; speedup vs baseline: 1.0021x; 1.0021x over previous
//
#include <hip/hip_runtime.h>
#include <stdint.h>

// LocalWindowAttention: B=2,T=4096,D=2048,H=16,HK=4,HD=128,WIN=512
// R4: swizzle baked into K/V^T *global* layout (producer epilogues), so
// attention staging uses identity per-lane addresses (coalesced) and LDS
// lands pre-swizzled (conflict-free reads, per R3).
//   kb:  within each head's 128-col group, 16B-chunk c stored at c^(token&15)
//   vT:  within each 128-key group,        16B-chunk c stored at c^(hd&15)
//   P in LDS: chunk c at c ^ ((row>>1)|((row&1)<<3))  (VALU writes, free choice)

typedef unsigned short u16;
typedef __attribute__((ext_vector_type(8))) short frag8;   // 8 bf16 = 4 VGPRs
typedef __attribute__((ext_vector_type(4))) float f32x4;   // MFMA acc

#define TILE 128

__device__ __forceinline__ u16 f2bf(float f) {
  union { float f; unsigned u; } c; c.f = f;
  unsigned u = c.u;
  return (u16)((u + 0x7fffu + ((u >> 16) & 1u)) >> 16);
}

// async global->LDS, 16B per lane; LDS dest = wave-uniform base + lane*16
__device__ __forceinline__ void async16(const u16* g, u16* l) {
  __builtin_amdgcn_global_load_lds((const __attribute__((address_space(1))) void*)g,
                                   (__attribute__((address_space(3))) void*)l, 16, 0, 0);
}

// ---- m97-style 128x128 GEMM core: A [M,K] row-major bf16, Bt = B^T [N,K] row-major
__device__ __forceinline__ void gemm_core(const u16* __restrict__ A, int lda,
                                          const u16* __restrict__ Bt, int ldb,
                                          int K, u16* As, u16* Bs, f32x4 acc[4][4]) {
  const int tid = threadIdx.x;
  const int lane = tid & 63, wave = tid >> 6;
  const int wr = wave >> 1, wc = wave & 1;
  const int quad = lane >> 4, l16 = lane & 15;
#pragma unroll
  for (int i = 0; i < 4; ++i)
#pragma unroll
    for (int j = 0; j < 4; ++j) acc[i][j] = (f32x4){0.f, 0.f, 0.f, 0.f};

  const int row0 = tid >> 2, offc = (tid & 3) * 8;  // 128 rows x 32 k, 16B chunks
  for (int k0 = 0; k0 < K; k0 += 32) {
#pragma unroll
    for (int r = 0; r < 2; ++r) {
      int row = r * 64 + row0;
      async16(A + (long)row * lda + k0 + offc, As + r * 2048 + wave * 512);
      async16(Bt + (long)row * ldb + k0 + offc, Bs + r * 2048 + wave * 512);
    }
    __syncthreads();
    frag8 af[4], bf[4];
#pragma unroll
    for (int i = 0; i < 4; ++i)
      af[i] = *(const frag8*)(As + (wr * 64 + i * 16 + l16) * 32 + quad * 8);
#pragma unroll
    for (int j = 0; j < 4; ++j)
      bf[j] = *(const frag8*)(Bs + (wc * 64 + j * 16 + l16) * 32 + quad * 8);
#pragma unroll
    for (int i = 0; i < 4; ++i)
#pragma unroll
      for (int j = 0; j < 4; ++j)
        acc[i][j] = __builtin_amdgcn_mfma_f32_16x16x32_bf16(af[i], bf[j], acc[i][j], 0, 0, 0);
    __syncthreads();
  }
}

#define EPI_COORDS                                             \
  const int lane = threadIdx.x & 63, wave = threadIdx.x >> 6;  \
  const int wr = wave >> 1, wc = wave & 1;                     \
  const int quad = lane >> 4, l16 = lane & 15;

__global__ __launch_bounds__(256) void k_gemm_bf16(const u16* __restrict__ A, int lda,
                                                   const u16* __restrict__ Bt, int ldb,
                                                   u16* __restrict__ C, int ldc, int K) {
  __shared__ alignas(16) u16 smem[2 * TILE * 32];
  f32x4 acc[4][4];
  gemm_core(A + (long)blockIdx.x * TILE * lda, lda,
            Bt + (long)blockIdx.y * TILE * ldb, ldb, K, smem, smem + TILE * 32, acc);
  EPI_COORDS
  u16* Ct = C + (long)blockIdx.x * TILE * ldc + (long)blockIdx.y * TILE;
#pragma unroll
  for (int i = 0; i < 4; ++i)
#pragma unroll
    for (int j = 0; j < 4; ++j) {
      int r0 = wr * 64 + i * 16 + quad * 4, cc = wc * 64 + j * 16 + l16;
#pragma unroll
      for (int r = 0; r < 4; ++r) Ct[(long)(r0 + r) * ldc + cc] = f2bf(acc[i][j][r]);
    }
}

// K-projection with swizzled column storage: within each head's 128-column
// group, 16B chunk c -> c ^ (token & 15).
__global__ __launch_bounds__(256) void k_gemm_kswz(const u16* __restrict__ A, int lda,
                                                   const u16* __restrict__ Bt, int ldb,
                                                   u16* __restrict__ C, int ldc, int K) {
  __shared__ alignas(16) u16 smem[2 * TILE * 32];
  f32x4 acc[4][4];
  gemm_core(A + (long)blockIdx.x * TILE * lda, lda,
            Bt + (long)blockIdx.y * TILE * ldb, ldb, K, smem, smem + TILE * 32, acc);
  EPI_COORDS
#pragma unroll
  for (int i = 0; i < 4; ++i)
#pragma unroll
    for (int j = 0; j < 4; ++j) {
      int cc = blockIdx.y * TILE + wc * 64 + j * 16 + l16;
      int base = cc & ~127, chunk = (cc >> 3) & 15, sub = cc & 7;
#pragma unroll
      for (int r = 0; r < 4; ++r) {
        long tok = (long)blockIdx.x * TILE + wr * 64 + i * 16 + quad * 4 + r;
        int ccs = base | ((chunk ^ ((int)tok & 15)) << 3) | sub;
        C[tok * ldc + ccs] = f2bf(acc[i][j][r]);
      }
    }
}

// V-projection writing C^T with swizzled key storage: within each 128-key
// group, 16B chunk c -> c ^ (hd_row & 15). ushort4 stores stay 8B-aligned.
__global__ __launch_bounds__(256) void k_gemm_vswz(const u16* __restrict__ A, int lda,
                                                   const u16* __restrict__ Bt, int ldb,
                                                   u16* __restrict__ Ct, int ldct, int K) {
  __shared__ alignas(16) u16 smem[2 * TILE * 32];
  f32x4 acc[4][4];
  gemm_core(A + (long)blockIdx.x * TILE * lda, lda,
            Bt + (long)blockIdx.y * TILE * ldb, ldb, K, smem, smem + TILE * 32, acc);
  EPI_COORDS
#pragma unroll
  for (int i = 0; i < 4; ++i)
#pragma unroll
    for (int j = 0; j < 4; ++j) {
      int n = blockIdx.y * TILE + wc * 64 + j * 16 + l16;           // hd row
      int m = blockIdx.x * TILE + wr * 64 + i * 16 + quad * 4;      // key
      int mbase = m & ~127, chunk = (m >> 3) & 15, sub = m & 7;
      int ms = mbase | ((chunk ^ (n & 15)) << 3) | sub;
      ushort4 o;
      o.x = f2bf(acc[i][j][0]); o.y = f2bf(acc[i][j][1]);
      o.z = f2bf(acc[i][j][2]); o.w = f2bf(acc[i][j][3]);
      *(ushort4*)(Ct + (long)n * ldct + ms) = o;
    }
}

__global__ __launch_bounds__(256) void k_gemm_f32(const u16* __restrict__ A, int lda,
                                                  const u16* __restrict__ Bt, int ldb,
                                                  float* __restrict__ C, int ldc, int K) {
  __shared__ alignas(16) u16 smem[2 * TILE * 32];
  f32x4 acc[4][4];
  gemm_core(A + (long)blockIdx.x * TILE * lda, lda,
            Bt + (long)blockIdx.y * TILE * ldb, ldb, K, smem, smem + TILE * 32, acc);
  EPI_COORDS
  float* Ct = C + (long)blockIdx.x * TILE * ldc + (long)blockIdx.y * TILE;
#pragma unroll
  for (int i = 0; i < 4; ++i)
#pragma unroll
    for (int j = 0; j < 4; ++j) {
      int r0 = wr * 64 + i * 16 + quad * 4, cc = wc * 64 + j * 16 + l16;
#pragma unroll
      for (int r = 0; r < 4; ++r) Ct[(long)(r0 + r) * ldc + cc] = acc[i][j][r];
    }
}

// ---- fused local-window attention --------------------------------------
// grid: x = qi (q 128-row block), y = blk, z = b*16 + h. Wave owns 32 q-rows.
// kb/vT are pre-swizzled in HBM; staging is identity (fully coalesced);
// LDS reads XOR by (row&15) as in R3 (verified conflict-free).
__global__ __launch_bounds__(256, 2) void k_attn(const u16* __restrict__ qb,
                                                 const u16* __restrict__ kb,
                                                 const u16* __restrict__ vT,
                                                 u16* __restrict__ O) {
  __shared__ alignas(16) u16 Ks[128 * 128];  // [key][hd] swizzled; P overlays
  __shared__ alignas(16) u16 Vs[128 * 128];  // [hd][key] swizzled
  const int tid = threadIdx.x, lane = tid & 63, wave = tid >> 6;
  const int quad = lane >> 4, l16 = lane & 15;
  const int qi = blockIdx.x, blk = blockIdx.y;
  const int b = blockIdx.z >> 4, h = blockIdx.z & 15, hk = h >> 2;
  const long tok_q = (long)b * 4096 + blk * 512 + qi * 128;
  const float scale = 0.08838834764831845f;  // 1/sqrt(128)

  // Q fragments for this wave's 32 rows, all of HD=128 (held across chunks)
  frag8 qf[2][4];
#pragma unroll
  for (int i = 0; i < 2; ++i)
#pragma unroll
    for (int kt = 0; kt < 4; ++kt)
      qf[i][kt] = *(const frag8*)(qb + (tok_q + wave * 32 + i * 16 + l16) * 2048 +
                                  h * 128 + kt * 32 + quad * 8);

  f32x4 o_acc[2][8];
  float m_r[2][4], l_r[2][4];
#pragma unroll
  for (int i = 0; i < 2; ++i) {
#pragma unroll
    for (int j = 0; j < 8; ++j) o_acc[i][j] = (f32x4){0.f, 0.f, 0.f, 0.f};
#pragma unroll
    for (int r = 0; r < 4; ++r) { m_r[i][r] = -1e30f; l_r[i][r] = 0.f; }
  }

  const int row_s = tid >> 4;                 // staging row within 16-row step
  const int off_s = (tid & 15) * 8;           // identity chunk offset (coalesced)
  u16* PsW = Ks + wave * 4096;                // wave's 32x128 P region
  const int psw = (l16 >> 1) | ((l16 & 1) << 3);  // P swizzle for read rows

  for (int ci = (blk ? qi : 4); ci <= 4 + qi; ++ci) {
    const long tok_k = (long)b * 4096 + (blk - 1) * 512 + ci * 128;
    const int mode = (ci == qi) ? 1 : ((ci == 4 + qi) ? 2 : 0);

    // stage K chunk [128 key][128 hd] and V chunk [128 hd][128 key]
#pragma unroll
    for (int r2 = 0; r2 < 8; ++r2) {
      int row = r2 * 16 + row_s;
      async16(kb + (tok_k + row) * 512 + hk * 128 + off_s, Ks + r2 * 2048 + wave * 512);
      async16(vT + ((long)hk * 128 + row) * 8192 + tok_k + off_s, Vs + r2 * 2048 + wave * 512);
    }
    __syncthreads();

    // S = Q @ K^T  (32 rows x 128 keys per wave)
    f32x4 s_acc[2][8];
#pragma unroll
    for (int i = 0; i < 2; ++i)
#pragma unroll
      for (int j = 0; j < 8; ++j) s_acc[i][j] = (f32x4){0.f, 0.f, 0.f, 0.f};
#pragma unroll
    for (int kt = 0; kt < 4; ++kt) {
      frag8 bfr[8];
#pragma unroll
      for (int j = 0; j < 8; ++j)
        bfr[j] = *(const frag8*)(Ks + (j * 16 + l16) * 128 + ((kt * 4 + quad) ^ l16) * 8);
#pragma unroll
      for (int i = 0; i < 2; ++i)
#pragma unroll
        for (int j = 0; j < 8; ++j)
          s_acc[i][j] = __builtin_amdgcn_mfma_f32_16x16x32_bf16(qf[i][kt], bfr[j], s_acc[i][j], 0, 0, 0);
    }

    // scale + mask + per-row chunk max
    float mc[2][4];
#pragma unroll
    for (int i = 0; i < 2; ++i)
#pragma unroll
      for (int r = 0; r < 4; ++r) mc[i][r] = -1e30f;
#pragma unroll
    for (int i = 0; i < 2; ++i)
#pragma unroll
      for (int j = 0; j < 8; ++j)
#pragma unroll
        for (int r = 0; r < 4; ++r) {
          int rl = wave * 32 + i * 16 + quad * 4 + r;  // row within 128-q-block
          int lk = j * 16 + l16;                       // key within chunk
          bool ok = (mode == 0) || (mode == 1 ? (lk > rl) : (lk <= rl));
          float s = ok ? s_acc[i][j][r] * scale : -1e30f;
          s_acc[i][j][r] = s;
          mc[i][r] = fmaxf(mc[i][r], s);
        }
#pragma unroll
    for (int o = 1; o < 16; o <<= 1)
#pragma unroll
      for (int i = 0; i < 2; ++i)
#pragma unroll
        for (int r = 0; r < 4; ++r)
          mc[i][r] = fmaxf(mc[i][r], __shfl_xor(mc[i][r], o));

    // online-softmax update
    float alpha[2][4];
#pragma unroll
    for (int i = 0; i < 2; ++i)
#pragma unroll
      for (int r = 0; r < 4; ++r) {
        float mn = fmaxf(m_r[i][r], mc[i][r]);
        alpha[i][r] = __expf(m_r[i][r] - mn);
        m_r[i][r] = mn;
        l_r[i][r] *= alpha[i][r];
      }
#pragma unroll
    for (int i = 0; i < 2; ++i)
#pragma unroll
      for (int j = 0; j < 8; ++j)
#pragma unroll
        for (int r = 0; r < 4; ++r) o_acc[i][j][r] *= alpha[i][r];

    float ps[2][4];
#pragma unroll
    for (int i = 0; i < 2; ++i)
#pragma unroll
      for (int r = 0; r < 4; ++r) ps[i][r] = 0.f;
#pragma unroll
    for (int i = 0; i < 2; ++i)
#pragma unroll
      for (int j = 0; j < 8; ++j)
#pragma unroll
        for (int r = 0; r < 4; ++r) {
          float s = s_acc[i][j][r];
          float e = __expf(s - m_r[i][r]);
          e = (s == -1e30f) ? 0.f : e;
          s_acc[i][j][r] = e;
          ps[i][r] += e;
        }
#pragma unroll
    for (int o = 1; o < 16; o <<= 1)
#pragma unroll
      for (int i = 0; i < 2; ++i)
#pragma unroll
        for (int r = 0; r < 4; ++r) ps[i][r] += __shfl_xor(ps[i][r], o);
#pragma unroll
    for (int i = 0; i < 2; ++i)
#pragma unroll
      for (int r = 0; r < 4; ++r) l_r[i][r] += ps[i][r];

    __syncthreads();  // all waves done reading Ks before P overlays it

    // P: C-layout regs -> LDS [row][key], swizzled (wave-private region)
#pragma unroll
    for (int i = 0; i < 2; ++i)
#pragma unroll
      for (int j = 0; j < 8; ++j)
#pragma unroll
        for (int r = 0; r < 4; ++r) {
          int rl = i * 16 + quad * 4 + r;
          int sw = ((rl & 15) >> 1) | ((rl & 1) << 3);
          int cc = 2 * j + (l16 >> 3);
          PsW[rl * 128 + ((cc ^ sw) * 8) + (l16 & 7)] = f2bf(s_acc[i][j][r]);
        }

    // O += P @ V
#pragma unroll
    for (int kt = 0; kt < 4; ++kt) {
      frag8 pf[2], vf[8];
#pragma unroll
      for (int i = 0; i < 2; ++i)
        pf[i] = *(const frag8*)(PsW + (i * 16 + l16) * 128 + (((kt * 4 + quad) ^ psw) * 8));
#pragma unroll
      for (int j = 0; j < 8; ++j)
        vf[j] = *(const frag8*)(Vs + (j * 16 + l16) * 128 + ((kt * 4 + quad) ^ l16) * 8);
#pragma unroll
      for (int i = 0; i < 2; ++i)
#pragma unroll
        for (int j = 0; j < 8; ++j)
          o_acc[i][j] = __builtin_amdgcn_mfma_f32_16x16x32_bf16(pf[i], vf[j], o_acc[i][j], 0, 0, 0);
    }
    __syncthreads();  // before next chunk's staging overwrites Ks/Vs
  }

  // epilogue: O / l
  float inv[2][4];
#pragma unroll
  for (int i = 0; i < 2; ++i)
#pragma unroll
    for (int r = 0; r < 4; ++r) inv[i][r] = 1.0f / l_r[i][r];
#pragma unroll
  for (int i = 0; i < 2; ++i)
#pragma unroll
    for (int j = 0; j < 8; ++j)
#pragma unroll
      for (int r = 0; r < 4; ++r) {
        long row = tok_q + wave * 32 + i * 16 + quad * 4 + r;
        O[row * 2048 + h * 128 + j * 16 + l16] = f2bf(o_acc[i][j][r] * inv[i][r]);
      }
}

__global__ void k_convert(const float4* __restrict__ x, ushort4* __restrict__ xb) {
  int i = blockIdx.x * 256 + threadIdx.x;
  float4 f = x[i];
  ushort4 o;
  o.x = f2bf(f.x); o.y = f2bf(f.y); o.z = f2bf(f.z); o.w = f2bf(f.w);
  xb[i] = o;
}

// W [K,N] fp32 -> W^T [N,K] bf16
__global__ void k_transpose(const float* __restrict__ W, u16* __restrict__ WT, int K, int N) {
  __shared__ float sh[32][33];
  int n0 = blockIdx.x * 32, k0 = blockIdx.y * 32;
  int tx = threadIdx.x, ty = threadIdx.y;  // (32, 8)
#pragma unroll
  for (int i = 0; i < 32; i += 8) sh[ty + i][tx] = W[(long)(k0 + ty + i) * N + n0 + tx];
  __syncthreads();
#pragma unroll
  for (int i = 0; i < 32; i += 8) WT[(long)(n0 + ty + i) * K + k0 + tx] = f2bf(sh[tx][ty + i]);
}

extern "C" void kernel_launch(void* const* d_in, const int* in_sizes, int n_in,
                              void* d_out, int out_size, void* d_ws, size_t ws_size,
                              hipStream_t stream) {
  const float* x  = (const float*)d_in[0];
  const float* Wq = (const float*)d_in[1];
  const float* Wk = (const float*)d_in[2];
  const float* Wv = (const float*)d_in[3];
  const float* Wo = (const float*)d_in[4];
  float* out = (float*)d_out;

  const long BT = 8192, D = 2048, NKV = 512;
  size_t off = 0;
  auto alloc = [&](size_t bytes) -> char* {
    off = (off + 255) & ~(size_t)255;
    char* p = (char*)d_ws + off;
    off += bytes;
    return p;
  };

  u16* xb  = (u16*)alloc((size_t)BT * D * 2);  // reused as attention output
  u16* WqT = (u16*)alloc((size_t)D * D * 2);
  u16* WkT = (u16*)alloc((size_t)NKV * D * 2);
  u16* WvT = (u16*)alloc((size_t)NKV * D * 2);
  u16* WoT = (u16*)alloc((size_t)D * D * 2);
  u16* qb  = (u16*)alloc((size_t)BT * D * 2);
  u16* kb  = (u16*)alloc((size_t)BT * NKV * 2);
  u16* vT  = (u16*)alloc((size_t)NKV * BT * 2);
  u16* Oa  = xb;

  k_convert<<<16384, 256, 0, stream>>>((const float4*)x, (ushort4*)xb);
  dim3 tb(32, 8);
  k_transpose<<<dim3(64, 64), tb, 0, stream>>>(Wq, WqT, 2048, 2048);
  k_transpose<<<dim3(16, 64), tb, 0, stream>>>(Wk, WkT, 2048, 512);
  k_transpose<<<dim3(16, 64), tb, 0, stream>>>(Wv, WvT, 2048, 512);
  k_transpose<<<dim3(64, 64), tb, 0, stream>>>(Wo, WoT, 2048, 2048);

  k_gemm_bf16<<<dim3(64, 16), 256, 0, stream>>>(xb, 2048, WqT, 2048, qb, 2048, 2048);
  k_gemm_kswz<<<dim3(64, 4),  256, 0, stream>>>(xb, 2048, WkT, 2048, kb, 512, 2048);
  k_gemm_vswz<<<dim3(64, 4),  256, 0, stream>>>(xb, 2048, WvT, 2048, vT, 8192, 2048);

  k_attn<<<dim3(4, 8, 32), 256, 0, stream>>>(qb, kb, vT, Oa);

  k_gemm_f32<<<dim3(64, 16), 256, 0, stream>>>(Oa, 2048, WoT, 2048, out, 2048, 2048);
}

// Round 5
// 660.966 us; speedup vs baseline: 1.0082x; 1.0061x over previous
//
#include <hip/hip_runtime.h>
#include <stdint.h>

// LocalWindowAttention: B=2,T=4096,D=2048,H=16,HK=4,HD=128,WIN=512
// R5: barrier-free fused attention. K/V fragments loaded DIRECT from global
// (coalesced 16B/lane, L1/L2-served; no LDS staging, no global_load_lds, no
// __syncthreads). LDS holds only the wave-private P transform buffer (32 KB
// -> 8 KB/wave) with the R3-verified swizzle. O assembled in LDS -> 16B
// coalesced stores. Projection GEMMs: m97-style async16 core (unchanged).

typedef unsigned short u16;
typedef __attribute__((ext_vector_type(8))) short frag8;   // 8 bf16 = 4 VGPRs
typedef __attribute__((ext_vector_type(4))) float f32x4;   // MFMA acc

#define TILE 128

__device__ __forceinline__ u16 f2bf(float f) {
  union { float f; unsigned u; } c; c.f = f;
  unsigned u = c.u;
  return (u16)((u + 0x7fffu + ((u >> 16) & 1u)) >> 16);
}

// async global->LDS, 16B per lane; LDS dest = wave-uniform base + lane*16
__device__ __forceinline__ void async16(const u16* g, u16* l) {
  __builtin_amdgcn_global_load_lds((const __attribute__((address_space(1))) void*)g,
                                   (__attribute__((address_space(3))) void*)l, 16, 0, 0);
}

// ---- m97-style 128x128 GEMM core: A [M,K] row-major bf16, Bt = B^T [N,K] row-major
__device__ __forceinline__ void gemm_core(const u16* __restrict__ A, int lda,
                                          const u16* __restrict__ Bt, int ldb,
                                          int K, u16* As, u16* Bs, f32x4 acc[4][4]) {
  const int tid = threadIdx.x;
  const int lane = tid & 63, wave = tid >> 6;
  const int wr = wave >> 1, wc = wave & 1;
  const int quad = lane >> 4, l16 = lane & 15;
#pragma unroll
  for (int i = 0; i < 4; ++i)
#pragma unroll
    for (int j = 0; j < 4; ++j) acc[i][j] = (f32x4){0.f, 0.f, 0.f, 0.f};

  const int row0 = tid >> 2, offc = (tid & 3) * 8;  // 128 rows x 32 k, 16B chunks
  for (int k0 = 0; k0 < K; k0 += 32) {
#pragma unroll
    for (int r = 0; r < 2; ++r) {
      int row = r * 64 + row0;
      async16(A + (long)row * lda + k0 + offc, As + r * 2048 + wave * 512);
      async16(Bt + (long)row * ldb + k0 + offc, Bs + r * 2048 + wave * 512);
    }
    __syncthreads();
    frag8 af[4], bf[4];
#pragma unroll
    for (int i = 0; i < 4; ++i)
      af[i] = *(const frag8*)(As + (wr * 64 + i * 16 + l16) * 32 + quad * 8);
#pragma unroll
    for (int j = 0; j < 4; ++j)
      bf[j] = *(const frag8*)(Bs + (wc * 64 + j * 16 + l16) * 32 + quad * 8);
#pragma unroll
    for (int i = 0; i < 4; ++i)
#pragma unroll
      for (int j = 0; j < 4; ++j)
        acc[i][j] = __builtin_amdgcn_mfma_f32_16x16x32_bf16(af[i], bf[j], acc[i][j], 0, 0, 0);
    __syncthreads();
  }
}

#define EPI_COORDS                                             \
  const int lane = threadIdx.x & 63, wave = threadIdx.x >> 6;  \
  const int wr = wave >> 1, wc = wave & 1;                     \
  const int quad = lane >> 4, l16 = lane & 15;

__global__ __launch_bounds__(256) void k_gemm_bf16(const u16* __restrict__ A, int lda,
                                                   const u16* __restrict__ Bt, int ldb,
                                                   u16* __restrict__ C, int ldc, int K) {
  __shared__ alignas(16) u16 smem[2 * TILE * 32];
  f32x4 acc[4][4];
  gemm_core(A + (long)blockIdx.x * TILE * lda, lda,
            Bt + (long)blockIdx.y * TILE * ldb, ldb, K, smem, smem + TILE * 32, acc);
  EPI_COORDS
  u16* Ct = C + (long)blockIdx.x * TILE * ldc + (long)blockIdx.y * TILE;
#pragma unroll
  for (int i = 0; i < 4; ++i)
#pragma unroll
    for (int j = 0; j < 4; ++j) {
      int r0 = wr * 64 + i * 16 + quad * 4, cc = wc * 64 + j * 16 + l16;
#pragma unroll
      for (int r = 0; r < 4; ++r) Ct[(long)(r0 + r) * ldc + cc] = f2bf(acc[i][j][r]);
    }
}

// writes C^T: contiguous 4-element store per acc tile (for V^T layout)
__global__ __launch_bounds__(256) void k_gemm_bf16t(const u16* __restrict__ A, int lda,
                                                    const u16* __restrict__ Bt, int ldb,
                                                    u16* __restrict__ Ct, int ldct, int K) {
  __shared__ alignas(16) u16 smem[2 * TILE * 32];
  f32x4 acc[4][4];
  gemm_core(A + (long)blockIdx.x * TILE * lda, lda,
            Bt + (long)blockIdx.y * TILE * ldb, ldb, K, smem, smem + TILE * 32, acc);
  EPI_COORDS
  u16* Cb = Ct + (long)blockIdx.y * TILE * ldct + (long)blockIdx.x * TILE;
#pragma unroll
  for (int i = 0; i < 4; ++i)
#pragma unroll
    for (int j = 0; j < 4; ++j) {
      int n = wc * 64 + j * 16 + l16, m0 = wr * 64 + i * 16 + quad * 4;
      ushort4 o;
      o.x = f2bf(acc[i][j][0]); o.y = f2bf(acc[i][j][1]);
      o.z = f2bf(acc[i][j][2]); o.w = f2bf(acc[i][j][3]);
      *(ushort4*)(Cb + (long)n * ldct + m0) = o;
    }
}

__global__ __launch_bounds__(256) void k_gemm_f32(const u16* __restrict__ A, int lda,
                                                  const u16* __restrict__ Bt, int ldb,
                                                  float* __restrict__ C, int ldc, int K) {
  __shared__ alignas(16) u16 smem[2 * TILE * 32];
  f32x4 acc[4][4];
  gemm_core(A + (long)blockIdx.x * TILE * lda, lda,
            Bt + (long)blockIdx.y * TILE * ldb, ldb, K, smem, smem + TILE * 32, acc);
  EPI_COORDS
  float* Ct = C + (long)blockIdx.x * TILE * ldc + (long)blockIdx.y * TILE;
#pragma unroll
  for (int i = 0; i < 4; ++i)
#pragma unroll
    for (int j = 0; j < 4; ++j) {
      int r0 = wr * 64 + i * 16 + quad * 4, cc = wc * 64 + j * 16 + l16;
#pragma unroll
      for (int r = 0; r < 4; ++r) Ct[(long)(r0 + r) * ldc + cc] = acc[i][j][r];
    }
}

// ---- fused local-window attention, barrier-free ------------------------
// grid: x = qi (q 128-row block), y = blk, z = b*16 + h. Wave owns 32 q-rows.
// K/V frags direct from global; LDS = wave-private P buffer only.
// P swizzle (verified R3/R4): write chunk cc at cc ^ ((rl>>1)|((rl&1)<<3)).
__global__ __launch_bounds__(256) void k_attn(const u16* __restrict__ qb,
                                              const u16* __restrict__ kb,
                                              const u16* __restrict__ vT,
                                              u16* __restrict__ O) {
  __shared__ alignas(16) u16 Ps[4 * 4096];   // 8 KB per wave: 32 rows x 128 keys
  const int tid = threadIdx.x, lane = tid & 63, wave = tid >> 6;
  const int quad = lane >> 4, l16 = lane & 15;
  const int qi = blockIdx.x, blk = blockIdx.y;
  const int b = blockIdx.z >> 4, h = blockIdx.z & 15, hk = h >> 2;
  const long tok_q = (long)b * 4096 + blk * 512 + qi * 128;
  const float scale = 0.08838834764831845f;  // 1/sqrt(128)

  // Q fragments for this wave's 32 rows, all of HD=128 (held across chunks)
  frag8 qf[2][4];
#pragma unroll
  for (int i = 0; i < 2; ++i)
#pragma unroll
    for (int kt = 0; kt < 4; ++kt)
      qf[i][kt] = *(const frag8*)(qb + (tok_q + wave * 32 + i * 16 + l16) * 2048 +
                                  h * 128 + kt * 32 + quad * 8);

  f32x4 o_acc[2][8];
  float m_r[2][4], l_r[2][4];
#pragma unroll
  for (int i = 0; i < 2; ++i) {
#pragma unroll
    for (int j = 0; j < 8; ++j) o_acc[i][j] = (f32x4){0.f, 0.f, 0.f, 0.f};
#pragma unroll
    for (int r = 0; r < 4; ++r) { m_r[i][r] = -1e30f; l_r[i][r] = 0.f; }
  }

  u16* PsW = Ps + wave * 4096;                    // wave-private 32x128 P region
  const int psw = (l16 >> 1) | ((l16 & 1) << 3);  // P swizzle for read rows

  for (int ci = (blk ? qi : 4); ci <= 4 + qi; ++ci) {
    const long tok_k = (long)b * 4096 + (blk - 1) * 512 + ci * 128;
    const int mode = (ci == qi) ? 1 : ((ci == 4 + qi) ? 2 : 0);

    // S = Q @ K^T  (32 rows x 128 keys per wave); K-frags direct from global
    f32x4 s_acc[2][8];
#pragma unroll
    for (int i = 0; i < 2; ++i)
#pragma unroll
      for (int j = 0; j < 8; ++j) s_acc[i][j] = (f32x4){0.f, 0.f, 0.f, 0.f};
#pragma unroll
    for (int kt = 0; kt < 4; ++kt) {
      frag8 kf[8];
#pragma unroll
      for (int j = 0; j < 8; ++j)
        kf[j] = *(const frag8*)(kb + (tok_k + j * 16 + l16) * 512 + hk * 128 + kt * 32 + quad * 8);
#pragma unroll
      for (int i = 0; i < 2; ++i)
#pragma unroll
        for (int j = 0; j < 8; ++j)
          s_acc[i][j] = __builtin_amdgcn_mfma_f32_16x16x32_bf16(qf[i][kt], kf[j], s_acc[i][j], 0, 0, 0);
    }

    // scale + mask + per-row chunk max
    float mc[2][4];
#pragma unroll
    for (int i = 0; i < 2; ++i)
#pragma unroll
      for (int r = 0; r < 4; ++r) mc[i][r] = -1e30f;
#pragma unroll
    for (int i = 0; i < 2; ++i)
#pragma unroll
      for (int j = 0; j < 8; ++j)
#pragma unroll
        for (int r = 0; r < 4; ++r) {
          int rl = wave * 32 + i * 16 + quad * 4 + r;  // row within 128-q-block
          int lk = j * 16 + l16;                       // key within chunk
          bool ok = (mode == 0) || (mode == 1 ? (lk > rl) : (lk <= rl));
          float s = ok ? s_acc[i][j][r] * scale : -1e30f;
          s_acc[i][j][r] = s;
          mc[i][r] = fmaxf(mc[i][r], s);
        }
#pragma unroll
    for (int o = 1; o < 16; o <<= 1)
#pragma unroll
      for (int i = 0; i < 2; ++i)
#pragma unroll
        for (int r = 0; r < 4; ++r)
          mc[i][r] = fmaxf(mc[i][r], __shfl_xor(mc[i][r], o));

    // online-softmax update
    float alpha[2][4];
#pragma unroll
    for (int i = 0; i < 2; ++i)
#pragma unroll
      for (int r = 0; r < 4; ++r) {
        float mn = fmaxf(m_r[i][r], mc[i][r]);
        alpha[i][r] = __expf(m_r[i][r] - mn);
        m_r[i][r] = mn;
        l_r[i][r] *= alpha[i][r];
      }
#pragma unroll
    for (int i = 0; i < 2; ++i)
#pragma unroll
      for (int j = 0; j < 8; ++j)
#pragma unroll
        for (int r = 0; r < 4; ++r) o_acc[i][j][r] *= alpha[i][r];

    float ps[2][4];
#pragma unroll
    for (int i = 0; i < 2; ++i)
#pragma unroll
      for (int r = 0; r < 4; ++r) ps[i][r] = 0.f;
#pragma unroll
    for (int i = 0; i < 2; ++i)
#pragma unroll
      for (int j = 0; j < 8; ++j)
#pragma unroll
        for (int r = 0; r < 4; ++r) {
          float s = s_acc[i][j][r];
          float e = __expf(s - m_r[i][r]);
          e = (s == -1e30f) ? 0.f : e;
          s_acc[i][j][r] = e;
          ps[i][r] += e;
        }
#pragma unroll
    for (int o = 1; o < 16; o <<= 1)
#pragma unroll
      for (int i = 0; i < 2; ++i)
#pragma unroll
        for (int r = 0; r < 4; ++r) ps[i][r] += __shfl_xor(ps[i][r], o);
#pragma unroll
    for (int i = 0; i < 2; ++i)
#pragma unroll
      for (int r = 0; r < 4; ++r) l_r[i][r] += ps[i][r];

    // P: C-layout regs -> LDS [row][key], swizzled (wave-private, no barrier)
#pragma unroll
    for (int i = 0; i < 2; ++i)
#pragma unroll
      for (int j = 0; j < 8; ++j)
#pragma unroll
        for (int r = 0; r < 4; ++r) {
          int rl = i * 16 + quad * 4 + r;
          int sw = ((rl & 15) >> 1) | ((rl & 1) << 3);
          int cc = 2 * j + (l16 >> 3);
          PsW[rl * 128 + ((cc ^ sw) * 8) + (l16 & 7)] = f2bf(s_acc[i][j][r]);
        }

    // O += P @ V; V-frags direct from global
#pragma unroll
    for (int kt = 0; kt < 4; ++kt) {
      frag8 pf[2], vf[8];
#pragma unroll
      for (int i = 0; i < 2; ++i)
        pf[i] = *(const frag8*)(PsW + (i * 16 + l16) * 128 + (((kt * 4 + quad) ^ psw) * 8));
#pragma unroll
      for (int j = 0; j < 8; ++j)
        vf[j] = *(const frag8*)(vT + ((long)hk * 128 + j * 16 + l16) * 8192 + tok_k + kt * 32 + quad * 8);
#pragma unroll
      for (int i = 0; i < 2; ++i)
#pragma unroll
        for (int j = 0; j < 8; ++j)
          o_acc[i][j] = __builtin_amdgcn_mfma_f32_16x16x32_bf16(pf[i], vf[j], o_acc[i][j], 0, 0, 0);
    }
  }

  // epilogue: normalize, assemble rows in (now-free) P region, 16B stores
  float inv[2][4];
#pragma unroll
  for (int i = 0; i < 2; ++i)
#pragma unroll
    for (int r = 0; r < 4; ++r) inv[i][r] = 1.0f / l_r[i][r];
#pragma unroll
  for (int i = 0; i < 2; ++i)
#pragma unroll
    for (int j = 0; j < 8; ++j)
#pragma unroll
      for (int r = 0; r < 4; ++r)
        PsW[(i * 16 + quad * 4 + r) * 128 + j * 16 + l16] = f2bf(o_acc[i][j][r] * inv[i][r]);
#pragma unroll
  for (int it = 0; it < 8; ++it) {
    int rr = it * 4 + quad;  // row within wave's 32
    int4 d = *(const int4*)(PsW + rr * 128 + l16 * 8);
    *(int4*)(O + (tok_q + wave * 32 + rr) * 2048 + h * 128 + l16 * 8) = d;
  }
}

__global__ void k_convert(const float4* __restrict__ x, ushort4* __restrict__ xb) {
  int i = blockIdx.x * 256 + threadIdx.x;
  float4 f = x[i];
  ushort4 o;
  o.x = f2bf(f.x); o.y = f2bf(f.y); o.z = f2bf(f.z); o.w = f2bf(f.w);
  xb[i] = o;
}

// W [K,N] fp32 -> W^T [N,K] bf16
__global__ void k_transpose(const float* __restrict__ W, u16* __restrict__ WT, int K, int N) {
  __shared__ float sh[32][33];
  int n0 = blockIdx.x * 32, k0 = blockIdx.y * 32;
  int tx = threadIdx.x, ty = threadIdx.y;  // (32, 8)
#pragma unroll
  for (int i = 0; i < 32; i += 8) sh[ty + i][tx] = W[(long)(k0 + ty + i) * N + n0 + tx];
  __syncthreads();
#pragma unroll
  for (int i = 0; i < 32; i += 8) WT[(long)(n0 + ty + i) * K + k0 + tx] = f2bf(sh[tx][ty + i]);
}

extern "C" void kernel_launch(void* const* d_in, const int* in_sizes, int n_in,
                              void* d_out, int out_size, void* d_ws, size_t ws_size,
                              hipStream_t stream) {
  const float* x  = (const float*)d_in[0];
  const float* Wq = (const float*)d_in[1];
  const float* Wk = (const float*)d_in[2];
  const float* Wv = (const float*)d_in[3];
  const float* Wo = (const float*)d_in[4];
  float* out = (float*)d_out;

  const long BT = 8192, D = 2048, NKV = 512;
  size_t off = 0;
  auto alloc = [&](size_t bytes) -> char* {
    off = (off + 255) & ~(size_t)255;
    char* p = (char*)d_ws + off;
    off += bytes;
    return p;
  };

  u16* xb  = (u16*)alloc((size_t)BT * D * 2);  // reused as attention output
  u16* WqT = (u16*)alloc((size_t)D * D * 2);
  u16* WkT = (u16*)alloc((size_t)NKV * D * 2);
  u16* WvT = (u16*)alloc((size_t)NKV * D * 2);
  u16* WoT = (u16*)alloc((size_t)D * D * 2);
  u16* qb  = (u16*)alloc((size_t)BT * D * 2);
  u16* kb  = (u16*)alloc((size_t)BT * NKV * 2);
  u16* vT  = (u16*)alloc((size_t)NKV * BT * 2);
  u16* Oa  = xb;

  k_convert<<<16384, 256, 0, stream>>>((const float4*)x, (ushort4*)xb);
  dim3 tb(32, 8);
  k_transpose<<<dim3(64, 64), tb, 0, stream>>>(Wq, WqT, 2048, 2048);
  k_transpose<<<dim3(16, 64), tb, 0, stream>>>(Wk, WkT, 2048, 512);
  k_transpose<<<dim3(16, 64), tb, 0, stream>>>(Wv, WvT, 2048, 512);
  k_transpose<<<dim3(64, 64), tb, 0, stream>>>(Wo, WoT, 2048, 2048);

  k_gemm_bf16 <<<dim3(64, 16), 256, 0, stream>>>(xb, 2048, WqT, 2048, qb, 2048, 2048);
  k_gemm_bf16 <<<dim3(64, 4),  256, 0, stream>>>(xb, 2048, WkT, 2048, kb, 512, 2048);
  k_gemm_bf16t<<<dim3(64, 4),  256, 0, stream>>>(xb, 2048, WvT, 2048, vT, 8192, 2048);

  k_attn<<<dim3(4, 8, 32), 256, 0, stream>>>(qb, kb, vT, Oa);

  k_gemm_f32<<<dim3(64, 16), 256, 0, stream>>>(Oa, 2048, WoT, 2048, out, 2048, 2048);
}